// Round 3
// baseline (250.999 us; speedup 1.0000x reference)
//
#include <hip/hip_runtime.h>

typedef _Float16 f16;
typedef _Float16 f16x8 __attribute__((ext_vector_type(8)));
typedef float f32x4 __attribute__((ext_vector_type(4)));

#define GLOBAL_AS __attribute__((address_space(1)))
#define LDS_AS __attribute__((address_space(3)))

// async global->LDS. LESSON (R8): LDS dest = wave-uniform base + lane*16 —
// NEVER issue under divergent control flow (schedule-dependent LDS corruption).
// Per-lane SOURCE address variation (clamps, swizzles) is fine.
__device__ __forceinline__ void async16(const void* g, void* l) {
  __builtin_amdgcn_global_load_lds((const GLOBAL_AS unsigned int*)g,
                                   (LDS_AS unsigned int*)l, 16, 0, 0);
}

__device__ __forceinline__ f16x8 cvt8v(const f32x4 x, const f32x4 y) {
  f16x8 h;
  h[0] = (f16)x[0]; h[1] = (f16)x[1]; h[2] = (f16)x[2]; h[3] = (f16)x[3];
  h[4] = (f16)y[0]; h[5] = (f16)y[1]; h[6] = (f16)y[2]; h[7] = (f16)y[3];
  return h;
}

// ---------------- weight conversion kernel (spike conversion fused into GEMM1)
// idx [0,819200):        w_hidden -> w2h (hi pad->800 | lo*2048 pad->1600)
// idx [819200,884736):   w_out -> w2o
__global__ __launch_bounds__(256) void conv_w(const float* __restrict__ wh,
                                              const float* __restrict__ wo,
                                              f16* __restrict__ w2h,
                                              f16* __restrict__ w2o) {
  int idx = blockIdx.x * 256 + threadIdx.x;  // grid 3456*256 = 884736 exactly
  if (idx < 819200) {
    int h = idx / 1600;
    int c = idx - h * 1600;
    f16 o = (f16)0.f;
    if (c < 784) {
      o = (f16)wh[h * 784 + c];
    } else if (c >= 800 && c < 1584) {
      float x = wh[h * 784 + (c - 800)];
      f16 hi = (f16)x;
      o = (f16)((x - (float)hi) * 2048.0f);  // exact residual, scaled past denormals
    }
    w2h[idx] = o;
  } else {
    int j = idx - 819200;
    w2o[j] = (f16)wo[j];
  }
}

// ---------------- f16 MFMA GEMM, BK=64, XOR-swizzled LDS (R4/R9-proven) ------------
// C[M][N_LD] = A[M][K] * B[N][K]^T (+ 2^-11 * A*B_lo^T if B_OFF_LO>0), output OUT.
// LDS: row r holds its granules permuted p = g ^ (r&mask): a quad's 16-row
// ds_read_b128 sweep hits all 32 banks (2 lanes/bank = free; R3->R4 fixed 14.3M
// conflicts). XCD_SWZ: 1-D grid of 4*256 blocks, the 4 n-blocks of an m-tile on
// one XCD's L2. __launch_bounds__(256,2) ONLY: (256,3) caps VGPR at 84 and
// spills the 128-VGPR accumulator (R7: 137 us, WRITE_SIZE +46 MB).
// A_F32 (R11): A is fp32 (raw spikes [.][784]); stage A as RAW FP32 via async16
// into a 32KB fp32 LDS tile (16 granules/row, slot = g ^ (r&15)); cvt to f16
// happens at fragment-read time in the compute phase (hides under MFMA on the
// VALU pipe). LESSON (R10/R11): reg-staging A (global->VGPR->cvt->ds_write)
// broke the DMA dataflow — 98-109 us, MfmaUtil ~20%; this keeps staging pure
// global_load_lds like R9. Pad/tail cols >=784 are dead (B hi AND lo are zero
// there), so tail source addresses clamp to stay in-bounds.
template <typename OUT, int N_LD, int A_STRIDE, int B_STRIDE, int NCH64,
          bool TAIL32, int B_OFF_LO, int KSPLIT_SPAN, bool XCD_SWZ, bool A_F32>
__global__ __launch_bounds__(256, 2) void gemm_f16(const void* __restrict__ A,
                                                   const f16* __restrict__ B,
                                                   OUT* __restrict__ C) {
  constexpr bool HAS_LO = (B_OFF_LO > 0);
  const f16* __restrict__ Ah = (const f16*)A;
  const float* __restrict__ Af = (const float*)A;
  __shared__ __align__(16) float lds_a32[A_F32 ? 128 * 64 : 8];
  __shared__ __align__(16) f16 lds_a[A_F32 ? 8 : 128 * 64];
  __shared__ __align__(16) f16 lds_bh[128 * 64];
  __shared__ __align__(16) f16 lds_bl[HAS_LO ? 128 * 64 : 8];
  const int t = threadIdx.x;
  const int lane = t & 63;
  const int wave = t >> 6;
  int bx, by;
  if (XCD_SWZ) {
    const int b = blockIdx.x;
    by = (b & 7) + 8 * (b >> 5);
    bx = (b >> 3) & 3;
  } else {
    bx = blockIdx.x;
    by = blockIdx.y;
  }
  const int m0 = by * 128;
  const int n0 = KSPLIT_SPAN ? 0 : bx * 128;
  const int kb = KSPLIT_SPAN ? bx * KSPLIT_SPAN : 0;
  OUT* Cp = KSPLIT_SPAN ? C + (size_t)bx * 32768 * N_LD : C;
  const int wm = (wave >> 1) * 64;
  const int wn = (wave & 1) * 64;
  const int row = lane & 15;
  const int quad = lane >> 4;

  f32x4 acch[4][4] = {};
  f32x4 accl[HAS_LO ? 4 : 1][4] = {};

  for (int c = 0; c < NCH64; ++c) {
    const int k0 = kb + c * 64;
    if constexpr (A_F32) {
      // A fp32: 128 rows x 16 granules(16B = 4 floats), slot = g ^ (r&15)
#pragma unroll
      for (int s = 0; s < 8; ++s) {
        const int j = t + s * 256;
        const int r = j >> 4;
        const int g = (j & 15) ^ (r & 15);
        async16(Af + (size_t)(m0 + r) * A_STRIDE + k0 + g * 4, &lds_a32[j * 4]);
      }
    }
#pragma unroll
    for (int s = 0; s < 4; ++s) {
      const int j = t + s * 256;
      const int r = j >> 3;
      const int g = (j & 7) ^ (r & 7);  // xor-swizzled source granule
      if constexpr (!A_F32) async16(Ah + (m0 + r) * A_STRIDE + k0 + g * 8, &lds_a[j * 8]);
      async16(B + (n0 + r) * B_STRIDE + k0 + g * 8, &lds_bh[j * 8]);
      if (HAS_LO)
        async16(B + (n0 + r) * B_STRIDE + B_OFF_LO + k0 + g * 8, &lds_bl[j * 8]);
    }
    __syncthreads();
#pragma unroll
    for (int ks = 0; ks < 2; ++ks) {
      f16x8 af[4], bh[4], bl[4];
#pragma unroll
      for (int tm = 0; tm < 4; ++tm) {
        const int ra = wm + tm * 16 + row;
        if constexpr (A_F32) {
          // granule pair G0 = ks*8 + quad*2 (even), G1 = G0+1; slot = G ^ (ra&15)
          const int s0 = (ks * 8 + quad * 2) ^ (ra & 15);
          f32x4 lo = *(const f32x4*)&lds_a32[ra * 64 + s0 * 4];
          f32x4 hi = *(const f32x4*)&lds_a32[ra * 64 + (s0 ^ 1) * 4];
          af[tm] = cvt8v(lo, hi);
        } else {
          const int p = (ks * 4 + quad) ^ (ra & 7);
          af[tm] = *(const f16x8*)&lds_a[ra * 64 + p * 8];
        }
      }
#pragma unroll
      for (int tn = 0; tn < 4; ++tn) {
        const int rb = wn + tn * 16 + row;
        const int p = (ks * 4 + quad) ^ (rb & 7);
        bh[tn] = *(const f16x8*)&lds_bh[rb * 64 + p * 8];
        if (HAS_LO) bl[tn] = *(const f16x8*)&lds_bl[rb * 64 + p * 8];
      }
#pragma unroll
      for (int tm = 0; tm < 4; ++tm)
#pragma unroll
        for (int tn = 0; tn < 4; ++tn) {
          acch[tm][tn] =
              __builtin_amdgcn_mfma_f32_16x16x32_f16(af[tm], bh[tn], acch[tm][tn], 0, 0, 0);
          if (HAS_LO)
            accl[tm][tn] =
                __builtin_amdgcn_mfma_f32_16x16x32_f16(af[tm], bl[tn], accl[tm][tn], 0, 0, 0);
        }
    }
    __syncthreads();
  }

  if (TAIL32) {  // one 32-wide K tail chunk; f16 rows have 4 granules (swz &3),
                 // fp32 rows have 8 granules (swz &7)
    const int k0 = kb + NCH64 * 64;
    if constexpr (A_F32) {
#pragma unroll
      for (int s = 0; s < 4; ++s) {
        const int j = t + s * 256;
        const int r = j >> 3;
        const int g = (j & 7) ^ (r & 7);
        int col = k0 + g * 4;
        if (col + 4 > A_STRIDE) col = k0;  // cols >=784 dead (B==0); stay in-bounds
        async16(Af + (size_t)(m0 + r) * A_STRIDE + col, &lds_a32[j * 4]);
      }
    }
#pragma unroll
    for (int s = 0; s < 2; ++s) {
      const int j = t + s * 256;
      const int r = j >> 2;
      const int g = (j & 3) ^ (r & 3);
      if constexpr (!A_F32) async16(Ah + (m0 + r) * A_STRIDE + k0 + g * 8, &lds_a[j * 8]);
      async16(B + (n0 + r) * B_STRIDE + k0 + g * 8, &lds_bh[j * 8]);
      if (HAS_LO)
        async16(B + (n0 + r) * B_STRIDE + B_OFF_LO + k0 + g * 8, &lds_bl[j * 8]);
    }
    __syncthreads();
    f16x8 af[4], bh[4], bl[4];
#pragma unroll
    for (int tm = 0; tm < 4; ++tm) {
      const int ra = wm + tm * 16 + row;
      if constexpr (A_F32) {
        const int s0 = (quad * 2) ^ (ra & 7);
        f32x4 lo = *(const f32x4*)&lds_a32[ra * 32 + s0 * 4];
        f32x4 hi = *(const f32x4*)&lds_a32[ra * 32 + (s0 ^ 1) * 4];
        af[tm] = cvt8v(lo, hi);
      } else {
        const int p = quad ^ (ra & 3);
        af[tm] = *(const f16x8*)&lds_a[ra * 32 + p * 8];
      }
    }
#pragma unroll
    for (int tn = 0; tn < 4; ++tn) {
      const int rb = wn + tn * 16 + row;
      const int p = quad ^ (rb & 3);
      bh[tn] = *(const f16x8*)&lds_bh[rb * 32 + p * 8];
      if (HAS_LO) bl[tn] = *(const f16x8*)&lds_bl[rb * 32 + p * 8];
    }
#pragma unroll
    for (int tm = 0; tm < 4; ++tm)
#pragma unroll
      for (int tn = 0; tn < 4; ++tn) {
        acch[tm][tn] =
            __builtin_amdgcn_mfma_f32_16x16x32_f16(af[tm], bh[tn], acch[tm][tn], 0, 0, 0);
        if (HAS_LO)
          accl[tm][tn] =
              __builtin_amdgcn_mfma_f32_16x16x32_f16(af[tm], bl[tn], accl[tm][tn], 0, 0, 0);
      }
  }

  // C/D layout: col = lane&15, row = quad*4 + r
#pragma unroll
  for (int tm = 0; tm < 4; ++tm)
#pragma unroll
    for (int tn = 0; tn < 4; ++tn)
#pragma unroll
      for (int r = 0; r < 4; ++r) {
        const int mm = m0 + wm + tm * 16 + quad * 4 + r;
        const int nn = n0 + wn + tn * 16 + row;
        float val = acch[tm][tn][r];
        if (HAS_LO) val += 4.8828125e-4f * accl[tm][tn][r];  // 2^-11 exact
        Cp[(size_t)mm * N_LD + nn] = (OUT)val;
      }
}

// ---------------- CUBA LIF scan (32-deep prefetch, f16 input) ----------------
// c_h f16: rounding rms ~1.4e-4 rel -> v-err rms ~4.5e-4 -> P(spike shift)~0.5%;
// expected absmax contribution ~0.1 (threshold 0.69). Halves the read traffic.
__global__ __launch_bounds__(256) void lif_scan(const f16* __restrict__ ch,
                                                f16* __restrict__ sh) {
  const int n = blockIdx.x * 256 + threadIdx.x;  // 65536 neurons
  f16 xa[32], xb[32];
#pragma unroll
  for (int j = 0; j < 32; ++j) xa[j] = ch[j * 65536 + n];
  float v = 0.f, cur = 0.f;
  for (int c = 0; c < 8; ++c) {
    const int nc = (c + 1) & 7;  // wrap: chunk-0 reload at c=7 is dead, L2-hot
#pragma unroll
    for (int j = 0; j < 32; ++j) xb[j] = ch[(nc * 32 + j) * 65536 + n];
#pragma unroll
    for (int j = 0; j < 32; ++j) {
      const int t = c * 32 + j;
      float x = (float)xa[j];
      v = v + 0.16666667f * (cur - v);  // v += dt*tau_mem_inv*(-v+i), old i
      cur = 0.8333333f * cur + x;       // i = i*(1-dt*tau_syn_inv) + x
      bool z = v > 1.0f;
      sh[t * 65536 + n] = z ? (f16)1.f : (f16)0.f;
      v = z ? 0.f : v;
    }
#pragma unroll
    for (int j = 0; j < 32; ++j) xa[j] = xb[j];
  }
}

// ---------------- CUBA LI scan, 4-way T-segmented (f16 co inputs) ----------------
// LI is linear; state decays (5/6)^d -> 64-step warm-run error ~1e-4. Sums the
// two K-split co streams (f16: direct out-err ~0.01, no threshold involved).
__global__ __launch_bounds__(256) void li_scan_seg(const f16* __restrict__ coA,
                                                   const f16* __restrict__ coB,
                                                   float* __restrict__ out) {
  const int tid = blockIdx.x * 256 + threadIdx.x;  // 65536
  const int n = tid & 16383;
  const int seg = tid >> 14;  // 0..3
  const int t0 = seg * 64;
  float v = 0.f, cur = 0.f;
  float xa[8], xb[8];
  if (seg) {
    const int w0 = t0 - 64;
#pragma unroll
    for (int j = 0; j < 8; ++j)
      xa[j] = (float)coA[(w0 + j) * 16384 + n] + (float)coB[(w0 + j) * 16384 + n];
    for (int c = 0; c < 8; ++c) {
      const int nb = w0 + (c + 1) * 8;  // c==7 prefetches t0..t0+7
#pragma unroll
      for (int j = 0; j < 8; ++j)
        xb[j] = (float)coA[(nb + j) * 16384 + n] + (float)coB[(nb + j) * 16384 + n];
#pragma unroll
      for (int j = 0; j < 8; ++j) {
        v = v + 0.16666667f * (cur - v);
        cur = 0.8333333f * cur + xa[j];
      }
#pragma unroll
      for (int j = 0; j < 8; ++j) xa[j] = xb[j];
    }
  } else {
#pragma unroll
    for (int j = 0; j < 8; ++j)
      xa[j] = (float)coA[j * 16384 + n] + (float)coB[j * 16384 + n];
  }
  for (int c = 0; c < 8; ++c) {
    if (c < 7) {
      const int nb = t0 + (c + 1) * 8;
#pragma unroll
      for (int j = 0; j < 8; ++j)
        xb[j] = (float)coA[(nb + j) * 16384 + n] + (float)coB[(nb + j) * 16384 + n];
    }
#pragma unroll
    for (int j = 0; j < 8; ++j) {
      const int t = t0 + c * 8 + j;
      v = v + 0.16666667f * (cur - v);
      cur = 0.8333333f * cur + xa[j];
      out[t * 16384 + n] = v;
    }
#pragma unroll
    for (int j = 0; j < 8; ++j) xa[j] = xb[j];
  }
}

// ---------------- launch ----------------
extern "C" void kernel_launch(void* const* d_in, const int* in_sizes, int n_in,
                              void* d_out, int out_size, void* d_ws, size_t ws_size,
                              hipStream_t stream) {
  const float* spikes = (const float*)d_in[0];    // [256][128][784]
  const float* w_hidden = (const float*)d_in[1];  // [512][784]
  const float* w_out = (const float*)d_in[2];     // [128][512]
  float* out = (float*)d_out;                     // [256][128][128]

  char* ws = (char*)d_ws;
  // layout (bytes):
  //   coA|coB f16       : 2x 8,388,608   (head of ws; A16 staging eliminated)
  //   w2h  [512][1600]  f16 :  1,638,400 (offset kept from prior layout)
  //   c_h  [32768][512] f16 : 33,554,432
  //   s_h  [32768][512] f16 : 33,554,432
  //   w2o  [128][512]   f16 :    131,072
  f16* coA = (f16*)ws;
  f16* coB = (f16*)(ws + 8388608);
  f16* w2h = (f16*)(ws + 52428800);
  f16* c_h = (f16*)(ws + 52428800 + 1638400);
  f16* s_h = (f16*)(ws + 52428800 + 1638400 + 33554432);
  f16* w2o = (f16*)(ws + 52428800 + 1638400 + 33554432 + 33554432);

  // weights-only conversion (spike conversion fused into GEMM1's A staging)
  conv_w<<<3456, 256, 0, stream>>>(w_hidden, w_out, w2h, w2o);

  // GEMM1: c_h[32768][512] (f16) = spikes_f32[32768][784] * w2h[512][800hi|800lo]^T
  gemm_f16<f16, 512, 784, 1600, 12, true, 800, 0, true, true>
      <<<1024, 256, 0, stream>>>(spikes, w2h, c_h);

  lif_scan<<<256, 256, 0, stream>>>(c_h, s_h);

  // GEMM2: co{A,B}[32768][128] (f16) = s_h[32768][512] * w2o[128][512]^T, K-split 2x256
  gemm_f16<f16, 128, 512, 512, 4, false, 0, 256, false, false>
      <<<dim3(2, 256), 256, 0, stream>>>(s_h, w2o, coA);

  li_scan_seg<<<256, 256, 0, stream>>>(coA, coB, out);
}

// Round 4
// 238.980 us; speedup vs baseline: 1.0503x; 1.0503x over previous
//
#include <hip/hip_runtime.h>

typedef _Float16 f16;
typedef _Float16 f16x8 __attribute__((ext_vector_type(8)));
typedef float f32x4 __attribute__((ext_vector_type(4)));

#define GLOBAL_AS __attribute__((address_space(1)))
#define LDS_AS __attribute__((address_space(3)))

// async global->LDS. LESSON (R8): LDS dest = wave-uniform base + lane*16 —
// NEVER issue under divergent control flow / per-lane conditional addressing
// (schedule-dependent LDS corruption; passed once, diverged under graph replay).
// LESSON (R10-R12): A-operand fusion of fp32->f16 conversion into GEMM1 is
// structurally net-negative in this 2-barrier schedule (reg-staging breaks the
// DMA dataflow: 98-109 us; fp32 DMA doubles the drain: 103 us; baseline 55-61).
// A must enter the GEMM as f16 via a separate memory-bound conversion pass.
__device__ __forceinline__ void async16(const void* g, void* l) {
  __builtin_amdgcn_global_load_lds((const GLOBAL_AS unsigned int*)g,
                                   (LDS_AS unsigned int*)l, 16, 0, 0);
}

// ---------------- merged conversion kernel (R7/R9-proven) ----------------
// blocks [0,12800):     spikes fp32 [32768][784] -> A16 f16 [32768][800] (pad 0)
// blocks [12800,16256): w_hidden -> w2h (hi pad->800 | lo*2048 pad->1600); w_out -> w2o
__global__ __launch_bounds__(256) void conv_all(const float* __restrict__ s,
                                                const float* __restrict__ wh,
                                                const float* __restrict__ wo,
                                                f16* __restrict__ a16,
                                                f16* __restrict__ w2h,
                                                f16* __restrict__ w2o) {
  if (blockIdx.x < 12800) {
    int idx = blockIdx.x * 256 + threadIdx.x;  // < 3,276,800
    int m = idx / 100;
    int g = idx - m * 100;
    f16x8 h = {};
    if (g < 98) {
      const float4* p = (const float4*)(s + (size_t)m * 784 + g * 8);
      float4 x = p[0];
      float4 y = p[1];
      h[0] = (f16)x.x; h[1] = (f16)x.y; h[2] = (f16)x.z; h[3] = (f16)x.w;
      h[4] = (f16)y.x; h[5] = (f16)y.y; h[6] = (f16)y.z; h[7] = (f16)y.w;
    }
    *(f16x8*)(a16 + (size_t)m * 800 + g * 8) = h;
  } else {
    int idx = (blockIdx.x - 12800) * 256 + threadIdx.x;
    if (idx < 819200) {
      int h = idx / 1600;
      int c = idx - h * 1600;
      f16 o = (f16)0.f;
      if (c < 784) {
        o = (f16)wh[h * 784 + c];
      } else if (c >= 800 && c < 1584) {
        float x = wh[h * 784 + (c - 800)];
        f16 hi = (f16)x;
        o = (f16)((x - (float)hi) * 2048.0f);  // exact residual, scaled past denormals
      }
      w2h[idx] = o;
    } else if (idx < 819200 + 65536) {
      int j = idx - 819200;
      w2o[j] = (f16)wo[j];
    }
  }
}

// ---------------- f16 MFMA GEMM, BK=64, XOR-swizzled LDS (R4/R9-proven) ------------
// C[M][N_LD] = A[M][K] * B[N][K]^T (+ 2^-11 * A*B_lo^T if B_OFF_LO>0), output OUT.
// LDS: row r holds its 8 16B-granules permuted p = g ^ (r&7): a quad's 16-row
// ds_read_b128 sweep hits all 32 banks (2 lanes/bank = free; R3->R4 fixed 14.3M
// conflicts). XCD_SWZ: 1-D grid of 4*256 blocks, the 4 n-blocks of an m-tile on
// one XCD's L2. __launch_bounds__(256,2) ONLY: (256,3) caps VGPR at 84 and
// spills the 128-VGPR accumulator (R7: 137 us, WRITE_SIZE +46 MB).
template <typename OUT, int N_LD, int A_STRIDE, int B_STRIDE, int NCH64,
          bool TAIL32, int B_OFF_LO, int KSPLIT_SPAN, bool XCD_SWZ>
__global__ __launch_bounds__(256, 2) void gemm_f16(const f16* __restrict__ A,
                                                   const f16* __restrict__ B,
                                                   OUT* __restrict__ C) {
  constexpr bool HAS_LO = (B_OFF_LO > 0);
  __shared__ __align__(16) f16 lds_a[128 * 64];
  __shared__ __align__(16) f16 lds_bh[128 * 64];
  __shared__ __align__(16) f16 lds_bl[HAS_LO ? 128 * 64 : 8];
  const int t = threadIdx.x;
  const int lane = t & 63;
  const int wave = t >> 6;
  int bx, by;
  if (XCD_SWZ) {
    const int b = blockIdx.x;
    by = (b & 7) + 8 * (b >> 5);
    bx = (b >> 3) & 3;
  } else {
    bx = blockIdx.x;
    by = blockIdx.y;
  }
  const int m0 = by * 128;
  const int n0 = KSPLIT_SPAN ? 0 : bx * 128;
  const int kb = KSPLIT_SPAN ? bx * KSPLIT_SPAN : 0;
  OUT* Cp = KSPLIT_SPAN ? C + (size_t)bx * 32768 * N_LD : C;
  const int wm = (wave >> 1) * 64;
  const int wn = (wave & 1) * 64;
  const int row = lane & 15;
  const int quad = lane >> 4;

  f32x4 acch[4][4] = {};
  f32x4 accl[HAS_LO ? 4 : 1][4] = {};

  for (int c = 0; c < NCH64; ++c) {
    const int k0 = kb + c * 64;
#pragma unroll
    for (int s = 0; s < 4; ++s) {
      const int j = t + s * 256;
      const int r = j >> 3;
      const int g = (j & 7) ^ (r & 7);  // xor-swizzled source granule
      async16(A + (m0 + r) * A_STRIDE + k0 + g * 8, &lds_a[j * 8]);
      async16(B + (n0 + r) * B_STRIDE + k0 + g * 8, &lds_bh[j * 8]);
      if (HAS_LO)
        async16(B + (n0 + r) * B_STRIDE + B_OFF_LO + k0 + g * 8, &lds_bl[j * 8]);
    }
    __syncthreads();
#pragma unroll
    for (int ks = 0; ks < 2; ++ks) {
      f16x8 af[4], bh[4], bl[4];
#pragma unroll
      for (int tm = 0; tm < 4; ++tm) {
        const int ra = wm + tm * 16 + row;
        const int p = (ks * 4 + quad) ^ (ra & 7);
        af[tm] = *(const f16x8*)&lds_a[ra * 64 + p * 8];
      }
#pragma unroll
      for (int tn = 0; tn < 4; ++tn) {
        const int rb = wn + tn * 16 + row;
        const int p = (ks * 4 + quad) ^ (rb & 7);
        bh[tn] = *(const f16x8*)&lds_bh[rb * 64 + p * 8];
        if (HAS_LO) bl[tn] = *(const f16x8*)&lds_bl[rb * 64 + p * 8];
      }
#pragma unroll
      for (int tm = 0; tm < 4; ++tm)
#pragma unroll
        for (int tn = 0; tn < 4; ++tn) {
          acch[tm][tn] =
              __builtin_amdgcn_mfma_f32_16x16x32_f16(af[tm], bh[tn], acch[tm][tn], 0, 0, 0);
          if (HAS_LO)
            accl[tm][tn] =
                __builtin_amdgcn_mfma_f32_16x16x32_f16(af[tm], bl[tn], accl[tm][tn], 0, 0, 0);
        }
    }
    __syncthreads();
  }

  if (TAIL32) {  // one 32-wide K tail chunk; rows have 4 granules, swizzle &3
    const int k0 = kb + NCH64 * 64;
#pragma unroll
    for (int s = 0; s < 2; ++s) {
      const int j = t + s * 256;
      const int r = j >> 2;
      const int g = (j & 3) ^ (r & 3);
      async16(A + (m0 + r) * A_STRIDE + k0 + g * 8, &lds_a[j * 8]);
      async16(B + (n0 + r) * B_STRIDE + k0 + g * 8, &lds_bh[j * 8]);
      if (HAS_LO)
        async16(B + (n0 + r) * B_STRIDE + B_OFF_LO + k0 + g * 8, &lds_bl[j * 8]);
    }
    __syncthreads();
    f16x8 af[4], bh[4], bl[4];
#pragma unroll
    for (int tm = 0; tm < 4; ++tm) {
      const int ra = wm + tm * 16 + row;
      const int p = quad ^ (ra & 3);
      af[tm] = *(const f16x8*)&lds_a[ra * 32 + p * 8];
    }
#pragma unroll
    for (int tn = 0; tn < 4; ++tn) {
      const int rb = wn + tn * 16 + row;
      const int p = quad ^ (rb & 3);
      bh[tn] = *(const f16x8*)&lds_bh[rb * 32 + p * 8];
      if (HAS_LO) bl[tn] = *(const f16x8*)&lds_bl[rb * 32 + p * 8];
    }
#pragma unroll
    for (int tm = 0; tm < 4; ++tm)
#pragma unroll
      for (int tn = 0; tn < 4; ++tn) {
        acch[tm][tn] =
            __builtin_amdgcn_mfma_f32_16x16x32_f16(af[tm], bh[tn], acch[tm][tn], 0, 0, 0);
        if (HAS_LO)
          accl[tm][tn] =
              __builtin_amdgcn_mfma_f32_16x16x32_f16(af[tm], bl[tn], accl[tm][tn], 0, 0, 0);
      }
  }

  // C/D layout: col = lane&15, row = quad*4 + r
#pragma unroll
  for (int tm = 0; tm < 4; ++tm)
#pragma unroll
    for (int tn = 0; tn < 4; ++tn)
#pragma unroll
      for (int r = 0; r < 4; ++r) {
        const int mm = m0 + wm + tm * 16 + quad * 4 + r;
        const int nn = n0 + wn + tn * 16 + row;
        float val = acch[tm][tn][r];
        if (HAS_LO) val += 4.8828125e-4f * accl[tm][tn][r];  // 2^-11 exact
        Cp[(size_t)mm * N_LD + nn] = (OUT)val;
      }
}

// ---------------- CUBA LIF scan (32-deep prefetch, f16 input) ----------------
// c_h f16: rounding rms ~1.4e-4 rel -> v-err rms ~4.5e-4 -> P(spike shift)~0.5%;
// expected absmax contribution ~0.1 (threshold 0.69). Halves the read traffic.
// 32-deep (was 16, R2): 4 MB in flight across 65536 threads at the fixed
// 4-waves/CU occupancy — the R2 bench attributes ~20-30 us of the pipeline
// improvement to this depth change.
__global__ __launch_bounds__(256) void lif_scan(const f16* __restrict__ ch,
                                                f16* __restrict__ sh) {
  const int n = blockIdx.x * 256 + threadIdx.x;  // 65536 neurons
  f16 xa[32], xb[32];
#pragma unroll
  for (int j = 0; j < 32; ++j) xa[j] = ch[j * 65536 + n];
  float v = 0.f, cur = 0.f;
  for (int c = 0; c < 8; ++c) {
    const int nc = (c + 1) & 7;  // wrap: chunk-0 reload at c=7 is dead, L2-hot
#pragma unroll
    for (int j = 0; j < 32; ++j) xb[j] = ch[(nc * 32 + j) * 65536 + n];
#pragma unroll
    for (int j = 0; j < 32; ++j) {
      const int t = c * 32 + j;
      float x = (float)xa[j];
      v = v + 0.16666667f * (cur - v);  // v += dt*tau_mem_inv*(-v+i), old i
      cur = 0.8333333f * cur + x;       // i = i*(1-dt*tau_syn_inv) + x
      bool z = v > 1.0f;
      sh[t * 65536 + n] = z ? (f16)1.f : (f16)0.f;
      v = z ? 0.f : v;
    }
#pragma unroll
    for (int j = 0; j < 32; ++j) xa[j] = xb[j];
  }
}

// ---------------- CUBA LI scan, 4-way T-segmented (f16 co inputs) ----------------
// LI is linear; state decays (5/6)^d -> 64-step warm-run error ~1e-4. Sums the
// two K-split co streams (f16: direct out-err ~0.01, no threshold involved).
__global__ __launch_bounds__(256) void li_scan_seg(const f16* __restrict__ coA,
                                                   const f16* __restrict__ coB,
                                                   float* __restrict__ out) {
  const int tid = blockIdx.x * 256 + threadIdx.x;  // 65536
  const int n = tid & 16383;
  const int seg = tid >> 14;  // 0..3
  const int t0 = seg * 64;
  float v = 0.f, cur = 0.f;
  float xa[8], xb[8];
  if (seg) {
    const int w0 = t0 - 64;
#pragma unroll
    for (int j = 0; j < 8; ++j)
      xa[j] = (float)coA[(w0 + j) * 16384 + n] + (float)coB[(w0 + j) * 16384 + n];
    for (int c = 0; c < 8; ++c) {
      const int nb = w0 + (c + 1) * 8;  // c==7 prefetches t0..t0+7
#pragma unroll
      for (int j = 0; j < 8; ++j)
        xb[j] = (float)coA[(nb + j) * 16384 + n] + (float)coB[(nb + j) * 16384 + n];
#pragma unroll
      for (int j = 0; j < 8; ++j) {
        v = v + 0.16666667f * (cur - v);
        cur = 0.8333333f * cur + xa[j];
      }
#pragma unroll
      for (int j = 0; j < 8; ++j) xa[j] = xb[j];
    }
  } else {
#pragma unroll
    for (int j = 0; j < 8; ++j)
      xa[j] = (float)coA[j * 16384 + n] + (float)coB[j * 16384 + n];
  }
  for (int c = 0; c < 8; ++c) {
    if (c < 7) {
      const int nb = t0 + (c + 1) * 8;
#pragma unroll
      for (int j = 0; j < 8; ++j)
        xb[j] = (float)coA[(nb + j) * 16384 + n] + (float)coB[(nb + j) * 16384 + n];
    }
#pragma unroll
    for (int j = 0; j < 8; ++j) {
      const int t = t0 + c * 8 + j;
      v = v + 0.16666667f * (cur - v);
      cur = 0.8333333f * cur + xa[j];
      out[t * 16384 + n] = v;
    }
#pragma unroll
    for (int j = 0; j < 8; ++j) xa[j] = xb[j];
  }
}

// ---------------- launch ----------------
extern "C" void kernel_launch(void* const* d_in, const int* in_sizes, int n_in,
                              void* d_out, int out_size, void* d_ws, size_t ws_size,
                              hipStream_t stream) {
  const float* spikes = (const float*)d_in[0];    // [256][128][784]
  const float* w_hidden = (const float*)d_in[1];  // [512][784]
  const float* w_out = (const float*)d_in[2];     // [128][512]
  float* out = (float*)d_out;                     // [256][128][128]

  char* ws = (char*)d_ws;
  // layout (bytes):
  //   A16  [32768][800] f16 : 52,428,800  (later aliased by coA|coB f16, 2x8,388,608)
  //   w2h  [512][1600]  f16 :  1,638,400
  //   c_h  [32768][512] f16 : 33,554,432
  //   s_h  [32768][512] f16 : 33,554,432
  //   w2o  [128][512]   f16 :    131,072
  f16* A16 = (f16*)ws;
  f16* coA = (f16*)ws;  // alias: A16 dead after GEMM1
  f16* coB = (f16*)(ws + 8388608);
  f16* w2h = (f16*)(ws + 52428800);
  f16* c_h = (f16*)(ws + 52428800 + 1638400);
  f16* s_h = (f16*)(ws + 52428800 + 1638400 + 33554432);
  f16* w2o = (f16*)(ws + 52428800 + 1638400 + 33554432 + 33554432);

  // merged conversions: spikes->A16 and weights->w2h/w2o in one dispatch
  conv_all<<<16256, 256, 0, stream>>>(spikes, w_hidden, w_out, A16, w2h, w2o);

  // GEMM1: c_h[32768][512] (f16) = A16[32768][800] * w2h[512][800hi|800lo]^T
  gemm_f16<f16, 512, 800, 1600, 12, true, 800, 0, true>
      <<<1024, 256, 0, stream>>>(A16, w2h, c_h);

  lif_scan<<<256, 256, 0, stream>>>(c_h, s_h);

  // GEMM2: co{A,B}[32768][128] (f16) = s_h[32768][512] * w2o[128][512]^T, K-split 2x256
  gemm_f16<f16, 128, 512, 512, 4, false, 0, 256, false>
      <<<dim3(2, 256), 256, 0, stream>>>(s_h, w2o, coA);

  li_scan_seg<<<256, 256, 0, stream>>>(coA, coB, out);
}

// Round 5
// 238.258 us; speedup vs baseline: 1.0535x; 1.0030x over previous
//
#include <hip/hip_runtime.h>

typedef _Float16 f16;
typedef _Float16 f16x8 __attribute__((ext_vector_type(8)));
typedef float f32x4 __attribute__((ext_vector_type(4)));

#define GLOBAL_AS __attribute__((address_space(1)))
#define LDS_AS __attribute__((address_space(3)))

// async global->LDS. LESSON (R8): LDS dest = wave-uniform base + lane*16 —
// NEVER issue under divergent control flow / per-lane conditional addressing
// (schedule-dependent LDS corruption; passed once, diverged under graph replay).
// LESSON (R10-R12): A-operand fusion of fp32->f16 conversion into GEMM1 is
// structurally net-negative in this 2-barrier schedule (reg-staging breaks the
// DMA dataflow: 98-109 us; fp32 DMA doubles the drain: 103 us; baseline 55-61).
// A must enter the GEMM as f16 via a separate memory-bound conversion pass.
// LEDGER (R13): across R1-R3, lif+gemm2+li+overhead ≈ 140 us robustly, vs ~40 us
// roofline -> the back half, not GEMM1, is the bottleneck. Hence fused_bgl below.
__device__ __forceinline__ void async16(const void* g, void* l) {
  __builtin_amdgcn_global_load_lds((const GLOBAL_AS unsigned int*)g,
                                   (LDS_AS unsigned int*)l, 16, 0, 0);
}

// ---------------- merged conversion kernel (R7/R9-proven; w2o dropped) ----------
// blocks [0,12800):     spikes fp32 [32768][784] -> A16 f16 [32768][800] (pad 0)
// blocks [12800,16000): w_hidden -> w2h (hi pad->800 | lo*2048 pad->1600)
__global__ __launch_bounds__(256) void conv_all(const float* __restrict__ s,
                                                const float* __restrict__ wh,
                                                f16* __restrict__ a16,
                                                f16* __restrict__ w2h) {
  if (blockIdx.x < 12800) {
    int idx = blockIdx.x * 256 + threadIdx.x;  // < 3,276,800
    int m = idx / 100;
    int g = idx - m * 100;
    f16x8 h = {};
    if (g < 98) {
      const float4* p = (const float4*)(s + (size_t)m * 784 + g * 8);
      float4 x = p[0];
      float4 y = p[1];
      h[0] = (f16)x.x; h[1] = (f16)x.y; h[2] = (f16)x.z; h[3] = (f16)x.w;
      h[4] = (f16)y.x; h[5] = (f16)y.y; h[6] = (f16)y.z; h[7] = (f16)y.w;
    }
    *(f16x8*)(a16 + (size_t)m * 800 + g * 8) = h;
  } else {
    int idx = (blockIdx.x - 12800) * 256 + threadIdx.x;
    if (idx < 819200) {
      int h = idx / 1600;
      int c = idx - h * 1600;
      f16 o = (f16)0.f;
      if (c < 784) {
        o = (f16)wh[h * 784 + c];
      } else if (c >= 800 && c < 1584) {
        float x = wh[h * 784 + (c - 800)];
        f16 hi = (f16)x;
        o = (f16)((x - (float)hi) * 2048.0f);  // exact residual, scaled past denormals
      }
      w2h[idx] = o;
    }
  }
}

// ---------------- f16 MFMA GEMM, BK=64, XOR-swizzled LDS (R4/R9-proven) ------------
// C[M][N_LD] = A[M][K] * B[N][K]^T (+ 2^-11 * A*B_lo^T if B_OFF_LO>0), output OUT.
// LDS: row r holds its 8 16B-granules permuted p = g ^ (r&7): a quad's 16-row
// ds_read_b128 sweep hits all 32 banks (2 lanes/bank = free; R3->R4 fixed 14.3M
// conflicts). XCD_SWZ: 1-D grid of 4*256 blocks, the 4 n-blocks of an m-tile on
// one XCD's L2. __launch_bounds__(256,2) ONLY: (256,3) caps VGPR at 84 and
// spills the 128-VGPR accumulator (R7: 137 us, WRITE_SIZE +46 MB).
template <typename OUT, int N_LD, int A_STRIDE, int B_STRIDE, int NCH64,
          bool TAIL32, int B_OFF_LO, int KSPLIT_SPAN, bool XCD_SWZ>
__global__ __launch_bounds__(256, 2) void gemm_f16(const f16* __restrict__ A,
                                                   const f16* __restrict__ B,
                                                   OUT* __restrict__ C) {
  constexpr bool HAS_LO = (B_OFF_LO > 0);
  __shared__ __align__(16) f16 lds_a[128 * 64];
  __shared__ __align__(16) f16 lds_bh[128 * 64];
  __shared__ __align__(16) f16 lds_bl[HAS_LO ? 128 * 64 : 8];
  const int t = threadIdx.x;
  const int lane = t & 63;
  const int wave = t >> 6;
  int bx, by;
  if (XCD_SWZ) {
    const int b = blockIdx.x;
    by = (b & 7) + 8 * (b >> 5);
    bx = (b >> 3) & 3;
  } else {
    bx = blockIdx.x;
    by = blockIdx.y;
  }
  const int m0 = by * 128;
  const int n0 = KSPLIT_SPAN ? 0 : bx * 128;
  const int kb = KSPLIT_SPAN ? bx * KSPLIT_SPAN : 0;
  OUT* Cp = KSPLIT_SPAN ? C + (size_t)bx * 32768 * N_LD : C;
  const int wm = (wave >> 1) * 64;
  const int wn = (wave & 1) * 64;
  const int row = lane & 15;
  const int quad = lane >> 4;

  f32x4 acch[4][4] = {};
  f32x4 accl[HAS_LO ? 4 : 1][4] = {};

  for (int c = 0; c < NCH64; ++c) {
    const int k0 = kb + c * 64;
#pragma unroll
    for (int s = 0; s < 4; ++s) {
      const int j = t + s * 256;
      const int r = j >> 3;
      const int g = (j & 7) ^ (r & 7);  // xor-swizzled source granule
      async16(A + (m0 + r) * A_STRIDE + k0 + g * 8, &lds_a[j * 8]);
      async16(B + (n0 + r) * B_STRIDE + k0 + g * 8, &lds_bh[j * 8]);
      if (HAS_LO)
        async16(B + (n0 + r) * B_STRIDE + B_OFF_LO + k0 + g * 8, &lds_bl[j * 8]);
    }
    __syncthreads();
#pragma unroll
    for (int ks = 0; ks < 2; ++ks) {
      f16x8 af[4], bh[4], bl[4];
#pragma unroll
      for (int tm = 0; tm < 4; ++tm) {
        const int ra = wm + tm * 16 + row;
        const int p = (ks * 4 + quad) ^ (ra & 7);
        af[tm] = *(const f16x8*)&lds_a[ra * 64 + p * 8];
      }
#pragma unroll
      for (int tn = 0; tn < 4; ++tn) {
        const int rb = wn + tn * 16 + row;
        const int p = (ks * 4 + quad) ^ (rb & 7);
        bh[tn] = *(const f16x8*)&lds_bh[rb * 64 + p * 8];
        if (HAS_LO) bl[tn] = *(const f16x8*)&lds_bl[rb * 64 + p * 8];
      }
#pragma unroll
      for (int tm = 0; tm < 4; ++tm)
#pragma unroll
        for (int tn = 0; tn < 4; ++tn) {
          acch[tm][tn] =
              __builtin_amdgcn_mfma_f32_16x16x32_f16(af[tm], bh[tn], acch[tm][tn], 0, 0, 0);
          if (HAS_LO)
            accl[tm][tn] =
                __builtin_amdgcn_mfma_f32_16x16x32_f16(af[tm], bl[tn], accl[tm][tn], 0, 0, 0);
        }
    }
    __syncthreads();
  }

  if (TAIL32) {  // one 32-wide K tail chunk; rows have 4 granules, swizzle &3
    const int k0 = kb + NCH64 * 64;
#pragma unroll
    for (int s = 0; s < 2; ++s) {
      const int j = t + s * 256;
      const int r = j >> 2;
      const int g = (j & 3) ^ (r & 3);
      async16(A + (m0 + r) * A_STRIDE + k0 + g * 8, &lds_a[j * 8]);
      async16(B + (n0 + r) * B_STRIDE + k0 + g * 8, &lds_bh[j * 8]);
      if (HAS_LO)
        async16(B + (n0 + r) * B_STRIDE + B_OFF_LO + k0 + g * 8, &lds_bl[j * 8]);
    }
    __syncthreads();
    f16x8 af[4], bh[4], bl[4];
#pragma unroll
    for (int tm = 0; tm < 4; ++tm) {
      const int ra = wm + tm * 16 + row;
      const int p = quad ^ (ra & 3);
      af[tm] = *(const f16x8*)&lds_a[ra * 32 + p * 8];
    }
#pragma unroll
    for (int tn = 0; tn < 4; ++tn) {
      const int rb = wn + tn * 16 + row;
      const int p = quad ^ (rb & 3);
      bh[tn] = *(const f16x8*)&lds_bh[rb * 32 + p * 8];
      if (HAS_LO) bl[tn] = *(const f16x8*)&lds_bl[rb * 32 + p * 8];
    }
#pragma unroll
    for (int tm = 0; tm < 4; ++tm)
#pragma unroll
      for (int tn = 0; tn < 4; ++tn) {
        acch[tm][tn] =
            __builtin_amdgcn_mfma_f32_16x16x32_f16(af[tm], bh[tn], acch[tm][tn], 0, 0, 0);
        if (HAS_LO)
          accl[tm][tn] =
              __builtin_amdgcn_mfma_f32_16x16x32_f16(af[tm], bl[tn], accl[tm][tn], 0, 0, 0);
      }
  }

  // C/D layout: col = lane&15, row = quad*4 + r
#pragma unroll
  for (int tm = 0; tm < 4; ++tm)
#pragma unroll
    for (int tn = 0; tn < 4; ++tn)
#pragma unroll
      for (int r = 0; r < 4; ++r) {
        const int mm = m0 + wm + tm * 16 + quad * 4 + r;
        const int nn = n0 + wn + tn * 16 + row;
        float val = acch[tm][tn][r];
        if (HAS_LO) val += 4.8828125e-4f * accl[tm][tn][r];  // 2^-11 exact
        Cp[(size_t)mm * N_LD + nn] = (OUT)val;
      }
}

// ---------------- fused LIF + GEMV(w_out) + LI: one block per batch b -----------
// After c_h, the only cross-t coupling is the two scan states; GEMM2 is pointwise
// in t and everything is per-b independent. Block b (512 thr, 8 waves): thread h
// runs neuron h's LIF; per 32-t chunk, spikes go to swizzled LDS (same proven
// granule^row&7 family as the GEMM), each wave MFMAs its 16-o tile against
// w_out B-fragments preloaded in VGPRs (K=512, 64 VGPR), co chunk lands in
// padded LDS, threads 0..127 advance LI and store. Eliminates s_h (67 MB) and
// co (60 MB) round-trips, two dispatches, the K-split f16 rounding of co, and
// the LI segmentation warm-up (exact scan).
__global__ __launch_bounds__(512, 2) void fused_bgl(const f16* __restrict__ ch,
                                                    const float* __restrict__ wo,
                                                    float* __restrict__ out) {
  const int b = blockIdx.x;   // 0..127
  const int tid = threadIdx.x;
  const int lane = tid & 63;
  const int wave = tid >> 6;  // o-tile index 0..7
  const int trow = lane & 15;
  const int quad = lane >> 4;

  __shared__ __align__(16) f16 s_lds[32 * 512];    // 32 KB, granule-swizzled
  __shared__ __align__(16) float co_lds[32][132];  // 16.9 KB, +4 pad rotates banks

  // B-fragments: o = wave*16 + trow; k(h) = ks*32 + quad*8 + j  (ks=0..15 -> K=512)
  // Same fragment geometry as the proven gemm B-read (row = lane&15, k-granule by quad).
  f16x8 bfrag[16];
  {
    const float* wp = wo + (wave * 16 + trow) * 512 + quad * 8;
#pragma unroll
    for (int ks = 0; ks < 16; ++ks) {
      const float4* p = (const float4*)(wp + ks * 32);
      float4 x = p[0];
      float4 y = p[1];
      f16x8 hh;
      hh[0] = (f16)x.x; hh[1] = (f16)x.y; hh[2] = (f16)x.z; hh[3] = (f16)x.w;
      hh[4] = (f16)y.x; hh[5] = (f16)y.y; hh[6] = (f16)y.z; hh[7] = (f16)y.w;
      bfrag[ks] = hh;
    }
  }

  const int h = tid;           // hidden neuron owned by this thread
  float v = 0.f, cur = 0.f;    // LIF state
  float lv = 0.f, lcur = 0.f;  // LI state (valid for tid<128)

  // c_h prefetch double buffer, 32 t deep (plain per-lane loads; uniform branch ok)
  f16 xa[32], xb[32];
#pragma unroll
  for (int j = 0; j < 32; ++j) xa[j] = ch[((size_t)(j * 128 + b)) * 512 + h];

  for (int c = 0; c < 8; ++c) {
    if (c < 7) {
#pragma unroll
      for (int j = 0; j < 32; ++j)
        xb[j] = ch[((size_t)(((c + 1) * 32 + j) * 128 + b)) * 512 + h];
    }
    // LIF 32 steps -> s_lds[t][granule (h>>3)^(t&7)] (2 lanes/bank, conflict-free)
#pragma unroll
    for (int j = 0; j < 32; ++j) {
      float x = (float)xa[j];
      v = v + 0.16666667f * (cur - v);  // v += dt*tau_mem_inv*(-v+i), old i
      cur = 0.8333333f * cur + x;       // i = i*(1-dt*tau_syn_inv) + x
      bool z = v > 1.0f;
      v = z ? 0.f : v;
      s_lds[j * 512 + (((h >> 3) ^ (j & 7)) << 3) + (h & 7)] = z ? (f16)1.f : (f16)0.f;
    }
#pragma unroll
    for (int j = 0; j < 32; ++j) xa[j] = xb[j];
    __syncthreads();

    // MFMA: co[32 t][o-tile(wave)] = s . w_out^T, K=512
    f32x4 acc0 = {};
    f32x4 acc1 = {};
#pragma unroll
    for (int ks = 0; ks < 16; ++ks) {
      const int G = ks * 4 + quad;  // unswizzled k-granule
      f16x8 a0 = *(const f16x8*)&s_lds[trow * 512 + ((G ^ (trow & 7)) << 3)];
      f16x8 a1 = *(const f16x8*)&s_lds[(16 + trow) * 512 + ((G ^ (trow & 7)) << 3)];
      acc0 = __builtin_amdgcn_mfma_f32_16x16x32_f16(a0, bfrag[ks], acc0, 0, 0, 0);
      acc1 = __builtin_amdgcn_mfma_f32_16x16x32_f16(a1, bfrag[ks], acc1, 0, 0, 0);
    }
    // C/D layout: col = lane&15 (=o within tile), row = quad*4 + r (=t within chunk)
#pragma unroll
    for (int r = 0; r < 4; ++r) {
      co_lds[quad * 4 + r][wave * 16 + trow] = acc0[r];
      co_lds[16 + quad * 4 + r][wave * 16 + trow] = acc1[r];
    }
    __syncthreads();

    // LI 32 steps (threads 0..127 = o); other waves proceed to next chunk's LIF —
    // safe: they touch s_lds only, and next co_lds write is behind the next barrier.
    if (tid < 128) {
#pragma unroll
      for (int j = 0; j < 32; ++j) {
        float x = co_lds[j][tid];
        lv = lv + 0.16666667f * (lcur - lv);
        lcur = 0.8333333f * lcur + x;
        out[((size_t)((c * 32 + j) * 128 + b)) * 128 + tid] = lv;
      }
    }
  }
}

// ---------------- launch ----------------
extern "C" void kernel_launch(void* const* d_in, const int* in_sizes, int n_in,
                              void* d_out, int out_size, void* d_ws, size_t ws_size,
                              hipStream_t stream) {
  const float* spikes = (const float*)d_in[0];    // [256][128][784]
  const float* w_hidden = (const float*)d_in[1];  // [512][784]
  const float* w_out = (const float*)d_in[2];     // [128][512]
  float* out = (float*)d_out;                     // [256][128][128]

  char* ws = (char*)d_ws;
  // layout (bytes):
  //   A16  [32768][800] f16 : 52,428,800
  //   w2h  [512][1600]  f16 :  1,638,400
  //   c_h  [32768][512] f16 : 33,554,432
  f16* A16 = (f16*)ws;
  f16* w2h = (f16*)(ws + 52428800);
  f16* c_h = (f16*)(ws + 52428800 + 1638400);

  // merged conversions: spikes->A16 and w_hidden->w2h in one dispatch
  conv_all<<<16000, 256, 0, stream>>>(spikes, w_hidden, A16, w2h);

  // GEMM1: c_h[32768][512] (f16) = A16[32768][800] * w2h[512][800hi|800lo]^T
  gemm_f16<f16, 512, 800, 1600, 12, true, 800, 0, true>
      <<<1024, 256, 0, stream>>>(A16, w2h, c_h);

  // fused back half: LIF scan + readout GEMV + LI scan, one block per batch b
  fused_bgl<<<128, 512, 0, stream>>>(c_h, w_out, out);
}